// Round 6
// baseline (227.390 us; speedup 1.0000x reference)
//
#include <hip/hip_runtime.h>
#include <math.h>

#define NN 5000
#define EE 80000
#define FIN 32
#define DD 64
#define XD 3
#define TD 6
#define PP1 256
#define PP2 32
#define HH 256
#define MM (NN + PP1 + PP2)   // 5288
#define CAP 64                // neighbor bucket capacity (Poisson mean 16; P(deg>64) ~ 1e-18)
#define NTILES 79             // ceil(5000/64) row tiles of S1
#define LOG_SCALE 1.4763057f
#define Y2SCALE (256.f / 5000.f)

// A2 split-K: 16 tiles x 40 chunks (kchunk=128); x2 split-K: 4 tiles x 79 chunks (kchunk=64)
#define A2CH 40
#define X2CH 79

// ---------------- workspace layout (bytes) ----------------
#define ACC_OFF   0u           // f32 [2]=ent1 [3]=ent2 ; int counter at +64
#define CNT_OFF   64u
#define DEG_OFF   256u         // deg[5000] int -> 20256
#define Y2A_OFF   20256u       // y2 accumulator [256] -> 21280
#define X2_OFF    21280u       // x2 [256][64] -> 86816
#define A2_OFF    86816u       // A2 [256][256] -> 348960
#define BM_OFF    348960u      // bitmask 25M bits -> 3,473,960
#define ZERO_BYTES 3473960u
// aliases inside BM region (bitmask dead after stage0):
#define PART_OFF  348960u      // softmax partials [79][2][256] f32 -> 510752
#define XW2_OFF   760608u      // [256][64] -> 826144
#define S2_OFF    826144u      // [256][32] -> 858912
#define ZE2_OFF   858912u      // [256][64] -> 924448
#define X3_OFF    924448u      // [32][64] -> 932640
#define Y3_OFF    932640u      // [32] -> 932768
// non-zeroed:
#define BUCK_OFF  3473984u     // bucket [5000][64] int -> 4753984
#define ZEP_OFF   4753984u     // ze1 [5000][64] -> 6033984
#define Z_OFF     6033984u     // z [5000][64] -> 7313984
#define S1_OFF    7313984u     // S1 [5000][256] -> 12433984
#define AS1_OFF   12433984u    // AS1 [5000][256] -> 17553984
#define CQ_OFF    17553984u    // c[256], q[256] -> 17556032
#define DRES_OFF  17556032u    // dres [5288][2] -> 17598336
// split-K partial pools (roomy path only):
#define PA2_OFF   17598336u    // [40][256][256] f32 -> 28084096
#define PX2_OFF   28084096u    // [79][256][64]  f32 -> 33261440
#define WS_ROOMY  33261504u

__device__ __forceinline__ float bsum256(float v, float* red) {
    int t = threadIdx.x;
    red[t] = v; __syncthreads();
    #pragma unroll
    for (int o = 128; o > 0; o >>= 1) {
        if (t < o) red[t] += red[t + o];
        __syncthreads();
    }
    float r = red[0]; __syncthreads();
    return r;
}

// fused: encoder GEMM w/ LDS-staged Wenc (blocks 0..1249) | edge dedupe (1250..1562) | prep c/q (1563)
__global__ __launch_bounds__(256) void stage0(
        const float* __restrict__ x0, const float* __restrict__ Wenc,
        float* __restrict__ z,
        const int* __restrict__ adj, unsigned int* __restrict__ mask,
        int* __restrict__ bucket, int* __restrict__ deg,
        const float* __restrict__ t, const float* __restrict__ W1,
        const float* __restrict__ b1, float* __restrict__ cq) {
    __shared__ float smem[FIN * DD + 4 * FIN];   // wx[32][64] | xr[4][32]
    int b = blockIdx.x;
    int tid = threadIdx.x;
    if (b < 1250) {
        float (*wx)[DD] = (float(*)[DD])smem;
        float (*xr)[FIN] = (float(*)[FIN])(smem + FIN * DD);
        int i0 = b << 2;
        int j = tid & 63;
        #pragma unroll
        for (int m = 0; m < 8; ++m) {
            int k = (tid >> 6) + (m << 2);
            wx[k][j] = Wenc[k * (DD + XD) + j];
        }
        if (tid < 128) xr[tid >> 5][tid & 31] = x0[(i0 + (tid >> 5)) * FIN + (tid & 31)];
        __syncthreads();
        int r = tid >> 6;
        float s = 0.f;
        #pragma unroll
        for (int k = 0; k < FIN; ++k) s = fmaf(xr[r][k], wx[k][j], s);
        z[(i0 + r) * DD + j] = tanhf(s) * LOG_SCALE;
    } else if (b < 1563) {
        int e = (b - 1250) * 256 + tid;
        if (e < EE) {
            int i = adj[e], jj = adj[EE + e];
            unsigned int key = (unsigned int)(i * NN + jj);
            unsigned int bit = 1u << (key & 31u);
            unsigned int old = atomicOr(&mask[key >> 5], bit);
            if (!(old & bit)) {
                int slot = atomicAdd(&deg[i], 1);
                if (slot < CAP) bucket[i * CAP + slot] = jj;
            }
        }
    } else {
        float* te = smem;
        int h = tid;
        if (h == 0) {
            float t0 = t[0];
            te[0] = t0 / 1e2f;
            te[1] = t0 / 1e3f;
            te[2] = t0 / 1e4f;
            te[3] = logf(t0 * 100.f + 1.f);
            te[4] = logf(t0 * 10.f + 1.f);
            te[5] = logf(t0 + 1.f);
        }
        __syncthreads();
        float c = b1[h];
        #pragma unroll
        for (int j2 = 0; j2 < TD; ++j2) c = fmaf(te[j2], W1[j2 * HH + h], c);
        float q = 0.f;
        #pragma unroll
        for (int j2 = 1; j2 < TD + XD; ++j2) { float w = W1[j2 * HH + h]; q = fmaf(w, w, q); }
        cq[h] = c;
        cq[HH + h] = q;
    }
}

// fused: S1 logits tiled GEMM + per-tile softmax partials (blocks 0..315)
//        | gather_z + (A@z)@We1 + tanh (blocks 316..1565)
__global__ __launch_bounds__(256) void stage1(
        const float* __restrict__ z, const float* __restrict__ Wp1,
        float* __restrict__ S1, float* __restrict__ part,
        const int* __restrict__ bucket, const int* __restrict__ deg,
        const float* __restrict__ We1, float* __restrict__ zep) {
    __shared__ float smem[2 * 64 * 64];   // 32 KB
    int b = blockIdx.x;
    int tid = threadIdx.x;
    if (b < NTILES * 4) {
        float (*sa)[64] = (float(*)[64])smem;            // z tile [row][k]
        float (*sb)[64] = (float(*)[64])(smem + 4096);   // Wp1 [k][col]
        int tm = (b >> 2) << 6;
        int tn = (b & 3) << 6;
        int r0 = tid >> 4, c0 = (tid & 15) << 2;
        const float4 zero4 = make_float4(0.f, 0.f, 0.f, 0.f);
        #pragma unroll
        for (int m = 0; m < 4; ++m) {
            int row = r0 + (m << 4);
            int gr = tm + row;
            *(float4*)&sa[row][c0] = (gr < NN) ? *(const float4*)&z[gr * DD + c0] : zero4;
            *(float4*)&sb[row][c0] = *(const float4*)&Wp1[row * PP1 + tn + c0];
        }
        __syncthreads();
        int tx = (tid & 15) << 2;
        int ty = (tid >> 4) << 2;
        float acc[4][4] = {};
        #pragma unroll
        for (int kk = 0; kk < 64; ++kk) {
            float a0 = sa[ty + 0][kk];
            float a1 = sa[ty + 1][kk];
            float a2 = sa[ty + 2][kk];
            float a3 = sa[ty + 3][kk];
            float4 bv = *(const float4*)&sb[kk][tx];
            acc[0][0] = fmaf(a0, bv.x, acc[0][0]);
            acc[0][1] = fmaf(a0, bv.y, acc[0][1]);
            acc[0][2] = fmaf(a0, bv.z, acc[0][2]);
            acc[0][3] = fmaf(a0, bv.w, acc[0][3]);
            acc[1][0] = fmaf(a1, bv.x, acc[1][0]);
            acc[1][1] = fmaf(a1, bv.y, acc[1][1]);
            acc[1][2] = fmaf(a1, bv.z, acc[1][2]);
            acc[1][3] = fmaf(a1, bv.w, acc[1][3]);
            acc[2][0] = fmaf(a2, bv.x, acc[2][0]);
            acc[2][1] = fmaf(a2, bv.y, acc[2][1]);
            acc[2][2] = fmaf(a2, bv.z, acc[2][2]);
            acc[2][3] = fmaf(a2, bv.w, acc[2][3]);
            acc[3][0] = fmaf(a3, bv.x, acc[3][0]);
            acc[3][1] = fmaf(a3, bv.y, acc[3][1]);
            acc[3][2] = fmaf(a3, bv.z, acc[3][2]);
            acc[3][3] = fmaf(a3, bv.w, acc[3][3]);
        }
        #pragma unroll
        for (int i2 = 0; i2 < 4; ++i2)
            #pragma unroll
            for (int j = 0; j < 4; ++j) acc[i2][j] *= LOG_SCALE;
        // write S1 (guarded)
        #pragma unroll
        for (int i2 = 0; i2 < 4; ++i2) {
            int gr = tm + ty + i2;
            if (gr < NN)
                *(float4*)&S1[gr * PP1 + tn + tx] =
                    make_float4(acc[i2][0], acc[i2][1], acc[i2][2], acc[i2][3]);
        }
        // per-thread column partials (mask invalid rows)
        int nvalid = NN - (tm + ty);
        nvalid = (nvalid < 0) ? 0 : (nvalid > 4 ? 4 : nvalid);
        float vm[4], vs[4];
        #pragma unroll
        for (int j = 0; j < 4; ++j) {
            float m = -3.0e38f;
            #pragma unroll
            for (int i2 = 0; i2 < 4; ++i2) if (i2 < nvalid) m = fmaxf(m, acc[i2][j]);
            float s = 0.f;
            #pragma unroll
            for (int i2 = 0; i2 < 4; ++i2) if (i2 < nvalid) s += expf(acc[i2][j] - m);
            vm[j] = m; vs[j] = s;
        }
        __syncthreads();   // smem dead (sa/sb consumed) -> reuse as reduction scratch
        float* redm = smem;          // [16][64]
        float* reds = smem + 1024;
        int g = tid >> 4;
        #pragma unroll
        for (int j = 0; j < 4; ++j) {
            redm[g * 64 + tx + j] = vm[j];
            reds[g * 64 + tx + j] = vs[j];
        }
        __syncthreads();
        if (tid < 64) {
            float M = -3.0e38f, S = 0.f;
            #pragma unroll
            for (int g2 = 0; g2 < 16; ++g2) {
                float m2 = redm[g2 * 64 + tid], s2 = reds[g2 * 64 + tid];
                float Mn = fmaxf(M, m2);
                S = S * expf(M - Mn) + s2 * expf(m2 - Mn);
                M = Mn;
            }
            int rt = tm >> 6;
            part[rt * 512 + tn + tid] = M;
            part[rt * 512 + 256 + tn + tid] = S;
        }
    } else {
        float (*zs)[DD] = (float(*)[DD])smem;
        int w = tid >> 6, d = tid & 63;
        int i = ((b - NTILES * 4) << 2) + w;
        int n = min(deg[i], CAP);
        const int* bk = bucket + i * CAP;
        float a0 = 0.f, a1 = 0.f, a2 = 0.f, a3 = 0.f;
        int s = 0;
        for (; s + 4 <= n; s += 4) {
            a0 += z[bk[s] * DD + d];
            a1 += z[bk[s + 1] * DD + d];
            a2 += z[bk[s + 2] * DD + d];
            a3 += z[bk[s + 3] * DD + d];
        }
        for (; s < n; ++s) a0 += z[bk[s] * DD + d];
        zs[w][d] = (a0 + a1) + (a2 + a3);
        __syncthreads();
        float acc = 0.f;
        #pragma unroll
        for (int k = 0; k < DD; ++k) acc = fmaf(zs[w][k], We1[k * DD + d], acc);
        zep[i * DD + d] = tanhf(acc);
    }
}

// normalize S1 in place + entropy + y-pool; chunk-combine (inline smax_finish) at block start
__global__ void smax_norm(float* __restrict__ S, const float* __restrict__ part,
                          const float* __restrict__ y, float* __restrict__ y2acc,
                          float* __restrict__ ent) {
    __shared__ float red[256];
    __shared__ float ybuf[4][64];
    __shared__ float cst[64];
    int rt = blockIdx.x % NTILES, ct = blockIdx.x / NTILES;
    int lc = threadIdx.x & 63, q = threadIdx.x >> 6;
    int c = (ct << 6) + lc;
    // combine 79 chunk partials -> cstat = colmax + ln(colsum)
    float M = -3.0e38f, Sv = 0.f;
    for (int ch = q; ch < NTILES; ch += 4) {
        float m2 = part[ch * 512 + c];
        float s2 = part[ch * 512 + 256 + c];
        float Mn = fmaxf(M, m2);
        Sv = Sv * expf(M - Mn) + s2 * expf(m2 - Mn);
        M = Mn;
    }
    red[threadIdx.x] = M; ybuf[q][lc] = Sv;
    __syncthreads();
    if (q == 0) {
        float Mm = red[lc], Ss = ybuf[0][lc];
        #pragma unroll
        for (int g = 1; g < 4; ++g) {
            float m2 = red[g * 64 + lc], s2 = ybuf[g][lc];
            float Mn = fmaxf(Mm, m2);
            Ss = Ss * expf(Mm - Mn) + s2 * expf(m2 - Mn);
            Mm = Mn;
        }
        cst[lc] = Mm + logf(Ss);
    }
    __syncthreads();
    float mxlns = cst[lc];
    float en = 0.f, ys = 0.f;
    #pragma unroll
    for (int k = 0; k < 16; ++k) {
        int r = (rt << 6) + (k << 2) + q;
        if (r < NN) {
            float v = S[r * PP1 + c];
            float s = expf(v - mxlns);
            S[r * PP1 + c] = s;
            en += s * (mxlns - v);
            ys = fmaf(s, y[r], ys);
        }
    }
    __syncthreads();                        // ybuf free again
    ybuf[q][lc] = ys;
    en = bsum256(en, red);                  // syncs cover ybuf visibility
    if (threadIdx.x == 0) atomicAdd(ent, en);
    if (q == 0) atomicAdd(&y2acc[c], ybuf[0][lc] + ybuf[1][lc] + ybuf[2][lc] + ybuf[3][lc]);
}

// AS1[i,c] = sum_{j in N(i)} S1[j,c]
__global__ void gather_as(const int* __restrict__ bucket, const int* __restrict__ deg,
                          const float* __restrict__ S1, float* __restrict__ AS1) {
    int i = blockIdx.x, c = threadIdx.x;
    int n = min(deg[i], CAP);
    const int* bk = bucket + i * CAP;
    float a0 = 0.f, a1 = 0.f, a2 = 0.f, a3 = 0.f;
    int s = 0;
    for (; s + 4 <= n; s += 4) {
        a0 += S1[bk[s] * PP1 + c];
        a1 += S1[bk[s + 1] * PP1 + c];
        a2 += S1[bk[s + 2] * PP1 + c];
        a3 += S1[bk[s + 3] * PP1 + c];
    }
    for (; s < n; ++s) a0 += S1[bk[s] * PP1 + c];
    AS1[i * PP1 + c] = (a0 + a1) + (a2 + a3);
}

// fused split-K TN GEMM, partials (no atomics).
// blocks 0..639: A2 partials (tile=b&15, chunk=b>>4, kchunk=128)
// blocks 640..955: x2 partials (tile=b2&3, chunk=b2>>2, kchunk=64)
__global__ __launch_bounds__(256) void gemm_fused(
        const float* __restrict__ S1, const float* __restrict__ AS1,
        const float* __restrict__ zep, float* __restrict__ PA2, float* __restrict__ PX2) {
    __shared__ float sa[32][64];
    __shared__ float sb[32][64];
    int b = blockIdx.x;
    const float* B;
    float* dst;
    int tm, tn, k0, k1, NB;
    if (b < 640) {
        int tile = b & 15, chunk = b >> 4;
        tm = (tile >> 2) << 6; tn = (tile & 3) << 6;
        k0 = chunk * 128; k1 = min(k0 + 128, NN);
        B = AS1; NB = PP1;
        dst = PA2 + chunk * (PP1 * PP1);
    } else {
        int b2 = b - 640;
        int tile = b2 & 3, chunk = b2 >> 2;
        tm = tile << 6; tn = 0;
        k0 = chunk * 64; k1 = min(k0 + 64, NN);
        B = zep; NB = DD;
        dst = PX2 + chunk * (PP1 * DD);
    }
    int tid = threadIdx.x;
    int tx = (tid & 15) << 2;
    int ty = (tid >> 4) << 2;
    int r0 = tid >> 4, c0 = (tid & 15) << 2;
    int r1 = (tid + 256) >> 4, c1 = c0;
    float acc[4][4] = {};
    const float4 z4 = make_float4(0.f, 0.f, 0.f, 0.f);
    for (int kb = k0; kb < k1; kb += 32) {
        int ka0 = kb + r0, ka1 = kb + r1;
        *(float4*)&sa[r0][c0] = (ka0 < k1) ? *(const float4*)&S1[ka0 * PP1 + tm + c0] : z4;
        *(float4*)&sa[r1][c1] = (ka1 < k1) ? *(const float4*)&S1[ka1 * PP1 + tm + c1] : z4;
        *(float4*)&sb[r0][c0] = (ka0 < k1) ? *(const float4*)&B[ka0 * NB + tn + c0] : z4;
        *(float4*)&sb[r1][c1] = (ka1 < k1) ? *(const float4*)&B[ka1 * NB + tn + c1] : z4;
        __syncthreads();
        #pragma unroll
        for (int kk = 0; kk < 32; ++kk) {
            float4 av = *(const float4*)&sa[kk][ty];
            float4 bv = *(const float4*)&sb[kk][tx];
            acc[0][0] = fmaf(av.x, bv.x, acc[0][0]);
            acc[0][1] = fmaf(av.x, bv.y, acc[0][1]);
            acc[0][2] = fmaf(av.x, bv.z, acc[0][2]);
            acc[0][3] = fmaf(av.x, bv.w, acc[0][3]);
            acc[1][0] = fmaf(av.y, bv.x, acc[1][0]);
            acc[1][1] = fmaf(av.y, bv.y, acc[1][1]);
            acc[1][2] = fmaf(av.y, bv.z, acc[1][2]);
            acc[1][3] = fmaf(av.y, bv.w, acc[1][3]);
            acc[2][0] = fmaf(av.z, bv.x, acc[2][0]);
            acc[2][1] = fmaf(av.z, bv.y, acc[2][1]);
            acc[2][2] = fmaf(av.z, bv.z, acc[2][2]);
            acc[2][3] = fmaf(av.z, bv.w, acc[2][3]);
            acc[3][0] = fmaf(av.w, bv.x, acc[3][0]);
            acc[3][1] = fmaf(av.w, bv.y, acc[3][1]);
            acc[3][2] = fmaf(av.w, bv.z, acc[3][2]);
            acc[3][3] = fmaf(av.w, bv.w, acc[3][3]);
        }
        __syncthreads();
    }
    #pragma unroll
    for (int i = 0; i < 4; ++i)
        *(float4*)&dst[(tm + ty + i) * NB + tn + tx] =
            make_float4(acc[i][0], acc[i][1], acc[i][2], acc[i][3]);
}

// sum partials -> A2 (scale 1) and x2 (scale Y2SCALE). grid 320x256.
__global__ void reduce_parts(const float* __restrict__ PA2, const float* __restrict__ PX2,
                             float* __restrict__ A2, float* __restrict__ x2) {
    int idx = blockIdx.x * 256 + threadIdx.x;
    if (idx < PP1 * PP1) {
        float s = 0.f;
        #pragma unroll 8
        for (int c = 0; c < A2CH; ++c) s += PA2[c * (PP1 * PP1) + idx];
        A2[idx] = s;
    } else {
        int e = idx - PP1 * PP1;
        float s = 0.f;
        #pragma unroll 8
        for (int c = 0; c < X2CH; ++c) s += PX2[c * (PP1 * DD) + e];
        x2[e] = s * Y2SCALE;
    }
}

// fallback (small ws): atomic split-K TN GEMM
__global__ void gemm_tn(const float* __restrict__ A, const float* __restrict__ B,
                        float* __restrict__ C, int M, int N, int K, int kchunk, float scale) {
    __shared__ float sa[32][64];
    __shared__ float sb[32][64];
    int tilesN = N >> 6;
    int tm = (blockIdx.x / tilesN) << 6;
    int tn = (blockIdx.x % tilesN) << 6;
    int k0 = blockIdx.y * kchunk;
    int k1 = min(k0 + kchunk, K);
    int tid = threadIdx.x;
    int tx = (tid & 15) << 2;
    int ty = (tid >> 4) << 2;
    float acc[4][4] = {};
    for (int kb = k0; kb < k1; kb += 32) {
        #pragma unroll
        for (int t = 0; t < 8; ++t) {
            int idx = tid + (t << 8);
            int r = idx >> 6, cc = idx & 63;
            int k = kb + r;
            sa[r][cc] = (k < k1) ? A[k * M + tm + cc] : 0.f;
            sb[r][cc] = (k < k1) ? B[k * N + tn + cc] : 0.f;
        }
        __syncthreads();
        #pragma unroll
        for (int kk = 0; kk < 32; ++kk) {
            float4 av = *(const float4*)&sa[kk][ty];
            float4 bv = *(const float4*)&sb[kk][tx];
            acc[0][0] = fmaf(av.x, bv.x, acc[0][0]);
            acc[0][1] = fmaf(av.x, bv.y, acc[0][1]);
            acc[0][2] = fmaf(av.x, bv.z, acc[0][2]);
            acc[0][3] = fmaf(av.x, bv.w, acc[0][3]);
            acc[1][0] = fmaf(av.y, bv.x, acc[1][0]);
            acc[1][1] = fmaf(av.y, bv.y, acc[1][1]);
            acc[1][2] = fmaf(av.y, bv.z, acc[1][2]);
            acc[1][3] = fmaf(av.y, bv.w, acc[1][3]);
            acc[2][0] = fmaf(av.z, bv.x, acc[2][0]);
            acc[2][1] = fmaf(av.z, bv.y, acc[2][1]);
            acc[2][2] = fmaf(av.z, bv.z, acc[2][2]);
            acc[2][3] = fmaf(av.z, bv.w, acc[2][3]);
            acc[3][0] = fmaf(av.w, bv.x, acc[3][0]);
            acc[3][1] = fmaf(av.w, bv.y, acc[3][1]);
            acc[3][2] = fmaf(av.w, bv.z, acc[3][2]);
            acc[3][3] = fmaf(av.w, bv.w, acc[3][3]);
        }
        __syncthreads();
    }
    #pragma unroll
    for (int i = 0; i < 4; ++i)
        #pragma unroll
        for (int j = 0; j < 4; ++j)
            atomicAdd(&C[(tm + ty + i) * N + tn + tx + j], acc[i][j] * scale);
}

// fused XW2 = x2@We2 (blocks 0..63) and S2 logits = x2@Wp2*LS (blocks 64..95)
__global__ void mm2_fused(const float* __restrict__ x2, const float* __restrict__ We2,
                          const float* __restrict__ Wp2, float* __restrict__ XW2,
                          float* __restrict__ S2) {
    int gid = blockIdx.x * 256 + threadIdx.x;
    if (gid < PP1 * DD) {
        int i = gid >> 6, j = gid & 63;
        float s = 0.f;
        #pragma unroll
        for (int k = 0; k < DD; ++k) s = fmaf(x2[i * DD + k], We2[k * DD + j], s);
        XW2[gid] = s;
    } else {
        int e = gid - PP1 * DD;
        int i = e >> 5, j = e & 31;
        float s = 0.f;
        #pragma unroll
        for (int k = 0; k < DD; ++k) s = fmaf(x2[i * DD + k], Wp2[k * PP2 + j], s);
        S2[e] = s * LOG_SCALE;
    }
}

// fused: S2 softmax (+ent+y3) on blocks 0..31 | ze2 = tanh(A2@XW2) on blocks 32..95
__global__ void level2b(float* __restrict__ S2, float* __restrict__ ent,
                        const float* __restrict__ y2acc, float* __restrict__ y3,
                        const float* __restrict__ A2, const float* __restrict__ XW2,
                        float* __restrict__ ze2) {
    __shared__ float red[256];
    int t = threadIdx.x;
    if (blockIdx.x < PP2) {
        int p = blockIdx.x;
        float l = S2[t * PP2 + p];
        red[t] = l; __syncthreads();
        #pragma unroll
        for (int o = 128; o > 0; o >>= 1) {
            if (t < o) red[t] = fmaxf(red[t], red[t + o]);
            __syncthreads();
        }
        float mx = red[0]; __syncthreads();
        float ex = expf(l - mx);
        float sum = bsum256(ex, red);
        float lns = logf(sum), inv = 1.f / sum;
        float s = ex * inv;
        S2[t * PP2 + p] = s;
        float en = s * (mx + lns - l);
        float ys = s * y2acc[t];
        en = bsum256(en, red);
        ys = bsum256(ys, red);
        if (t == 0) {
            atomicAdd(ent, en);
            y3[p] = ys * ((32.f / 256.f) * Y2SCALE);
        }
    } else {
        int gid = (blockIdx.x - PP2) * 256 + t;
        int i = gid >> 6, j = gid & 63;
        const float* a = A2 + i * PP1;
        float s = 0.f;
        #pragma unroll 16
        for (int k = 0; k < PP1; ++k) s = fmaf(a[k], XW2[k * DD + j], s);
        ze2[gid] = tanhf(s);
    }
}

// x3[j,d] = (32/256) * sum_i S2[i,j]*ze2[i,d]
__global__ void pool_x3(const float* __restrict__ S2, const float* __restrict__ ze2,
                        float* __restrict__ x3) {
    __shared__ float pr[4][64];
    int j = blockIdx.x;
    int d = threadIdx.x & 63, q = threadIdx.x >> 6;
    float a = 0.f;
    #pragma unroll 4
    for (int i = q * 64; i < q * 64 + 64; ++i)
        a = fmaf(S2[i * PP2 + j], ze2[i * DD + d], a);
    pr[q][d] = a;
    __syncthreads();
    if (q == 0) x3[j * DD + d] = (pr[0][d] + pr[1][d] + pr[2][d] + pr[3][d]) * (32.f / 256.f);
}

// decoder: 8 rows per block; last block (device counter) reduces dres + emits final loss
__global__ __launch_bounds__(256) void decoder8(
        const float* __restrict__ z, const float* __restrict__ x2,
        const float* __restrict__ x3, const float* __restrict__ y,
        const float* __restrict__ y2acc, const float* __restrict__ y3,
        const float* __restrict__ W1, const float* __restrict__ W2,
        const float* __restrict__ b2, const float* __restrict__ cq,
        float* __restrict__ dres, int* __restrict__ cnt,
        const float* __restrict__ acc, float* __restrict__ out) {
    __shared__ float zr[8][DD];
    __shared__ float rw[8][3][4];
    __shared__ int lastflag;
    int t = threadIdx.x;
    int i0 = blockIdx.x << 3;
    #pragma unroll
    for (int e = t; e < 512; e += 256) {
        int r = e >> 6, d = e & 63;
        int i = i0 + r;
        float v;
        if (i < NN) v = z[i * DD + d];
        else if (i < NN + PP1) v = x2[(i - NN) * DD + d];
        else v = x3[(i - NN - PP1) * DD + d];
        zr[r][d] = v;
    }
    __syncthreads();
    int h = t;
    float c0 = cq[h];
    float a[8];
    #pragma unroll
    for (int r = 0; r < 8; ++r) a[r] = c0;
    #pragma unroll 8
    for (int k = 0; k < DD; ++k) {
        float w = W1[(TD + XD + k) * HH + h];
        #pragma unroll
        for (int r = 0; r < 8; ++r) a[r] = fmaf(zr[r][k], w, a[r]);
    }
    float w2h = W2[h], w1h = W1[h], qh = cq[HH + h];
    float pu[8], pg[8], pl[8];
    #pragma unroll
    for (int r = 0; r < 8; ++r) {
        float th = tanhf(a[r]);
        float g1 = 1.f - th * th;
        pu[r] = w2h * th;
        pg[r] = w2h * g1 * w1h;
        pl[r] = w2h * (-2.f * th * g1) * qh;
    }
    #pragma unroll
    for (int o = 32; o > 0; o >>= 1) {
        #pragma unroll
        for (int r = 0; r < 8; ++r) {
            pu[r] += __shfl_xor(pu[r], o);
            pg[r] += __shfl_xor(pg[r], o);
            pl[r] += __shfl_xor(pl[r], o);
        }
    }
    int wave = t >> 6, lane = t & 63;
    if (lane == 0) {
        #pragma unroll
        for (int r = 0; r < 8; ++r) {
            rw[r][0][wave] = pu[r];
            rw[r][1][wave] = pg[r];
            rw[r][2][wave] = pl[r];
        }
    }
    __syncthreads();
    if (t < 8) {
        int r = t, i = i0 + r;
        float su = rw[r][0][0] + rw[r][0][1] + rw[r][0][2] + rw[r][0][3];
        float sg = rw[r][1][0] + rw[r][1][1] + rw[r][1][2] + rw[r][1][3];
        float sl = rw[r][2][0] + rw[r][2][1] + rw[r][2][2] + rw[r][2][3];
        float u = su + b2[0];
        float yv = (i < NN) ? y[i]
                 : (i < NN + PP1) ? y2acc[i - NN] * Y2SCALE
                 : y3[i - NN - PP1];
        float du = u - yv;
        float res = sg - sl;
        dres[i * 2] = du * du;
        dres[i * 2 + 1] = res * res;
        __threadfence();                 // make this thread's dres writes device-visible
    }
    __syncthreads();
    if (t == 0) lastflag = atomicAdd(cnt, 1);
    __syncthreads();
    if (lastflag == (MM / 8) - 1) {
        __threadfence();                 // acquire side
        float* red = (float*)zr;
        float sd = 0.f, sp = 0.f;
        for (int i = t; i < MM; i += 256) {
            sd += dres[i * 2];
            sp += dres[i * 2 + 1];
        }
        sd = bsum256(sd, red);
        sp = bsum256(sp, red);
        if (t == 0)
            out[0] = sd * (1.f / MM) + sp * (1.f / MM)
                   + acc[2] * (1.f / (float)(NN * PP1)) + acc[3] * (1.f / (float)(PP1 * PP2));
    }
}

extern "C" void kernel_launch(void* const* d_in, const int* in_sizes, int n_in,
                              void* d_out, int out_size, void* d_ws, size_t ws_size,
                              hipStream_t stream) {
    const float* x0   = (const float*)d_in[0];
    const int*   adj  = (const int*)d_in[1];
    const float* t    = (const float*)d_in[2];
    const float* y    = (const float*)d_in[3];
    const float* Wenc = (const float*)d_in[4];
    const float* Wp1  = (const float*)d_in[5];
    const float* Wp2  = (const float*)d_in[6];
    const float* We1  = (const float*)d_in[7];
    const float* We2  = (const float*)d_in[8];
    const float* W1   = (const float*)d_in[9];
    const float* b1   = (const float*)d_in[10];
    const float* W2   = (const float*)d_in[11];
    const float* b2   = (const float*)d_in[12];

    char* ws = (char*)d_ws;
    float* acc   = (float*)(ws + ACC_OFF);
    int*   cnt   = (int*)(ws + CNT_OFF);
    int*   deg   = (int*)(ws + DEG_OFF);
    float* y2acc = (float*)(ws + Y2A_OFF);
    float* x2    = (float*)(ws + X2_OFF);
    float* A2    = (float*)(ws + A2_OFF);
    unsigned int* mask = (unsigned int*)(ws + BM_OFF);
    float* part  = (float*)(ws + PART_OFF);
    float* XW2   = (float*)(ws + XW2_OFF);
    float* S2    = (float*)(ws + S2_OFF);
    float* ze2   = (float*)(ws + ZE2_OFF);
    float* x3    = (float*)(ws + X3_OFF);
    float* y3    = (float*)(ws + Y3_OFF);
    int*   buck  = (int*)(ws + BUCK_OFF);
    float* zep   = (float*)(ws + ZEP_OFF);
    float* z     = (float*)(ws + Z_OFF);
    float* S1    = (float*)(ws + S1_OFF);
    float* AS1   = (float*)(ws + AS1_OFF);
    float* cq    = (float*)(ws + CQ_OFF);
    float* dres  = (float*)(ws + DRES_OFF);
    float* PA2   = (float*)(ws + PA2_OFF);
    float* PX2   = (float*)(ws + PX2_OFF);

    hipMemsetAsync(ws, 0, ZERO_BYTES, stream);

    stage0<<<1564, 256, 0, stream>>>(x0, Wenc, z, adj, mask, buck, deg, t, W1, b1, cq);
    stage1<<<NTILES * 4 + NN / 4, 256, 0, stream>>>(z, Wp1, S1, part, buck, deg, We1, zep);
    smax_norm<<<NTILES * 4, 256, 0, stream>>>(S1, part, y, y2acc, &acc[2]);
    gather_as<<<NN, PP1, 0, stream>>>(buck, deg, S1, AS1);
    if (ws_size >= WS_ROOMY) {
        gemm_fused<<<640 + 316, 256, 0, stream>>>(S1, AS1, zep, PA2, PX2);
        reduce_parts<<<320, 256, 0, stream>>>(PA2, PX2, A2, x2);
    } else {
        gemm_tn<<<dim3(4, 32), 256, 0, stream>>>(S1, zep, x2, PP1, DD, NN, 157, Y2SCALE);
        gemm_tn<<<dim3(16, 16), 256, 0, stream>>>(S1, AS1, A2, PP1, PP1, NN, 313, 1.f);
    }
    mm2_fused<<<96, 256, 0, stream>>>(x2, We2, Wp2, XW2, S2);
    level2b<<<96, 256, 0, stream>>>(S2, &acc[3], y2acc, y3, A2, XW2, ze2);
    pool_x3<<<PP2, 256, 0, stream>>>(S2, ze2, x3);
    decoder8<<<MM / 8, 256, 0, stream>>>(z, x2, x3, y, y2acc, y3, W1, W2, b2, cq,
                                         dres, cnt, acc, (float*)d_out);
}